// Round 5
// baseline (395.772 us; speedup 1.0000x reference)
//
#include <hip/hip_runtime.h>
#include <cstdint>
#include <math.h>

// Problem constants
constexpr int NH  = 16;    // heads
constexpr int DKH = 64;    // head dim
constexpr int SEQ = 1024;  // LT == LS
constexpr int NB  = 4;     // batch
constexpr int DM  = 1024;  // d_model
constexpr int DF  = 4096;  // ffn dim

typedef __bf16 bf16;
typedef __bf16 bf16x4 __attribute__((ext_vector_type(4)));
typedef __bf16 bf16x8 __attribute__((ext_vector_type(8)));
typedef float  f32x4  __attribute__((ext_vector_type(4)));

#define MFMA16(a, b, c) __builtin_amdgcn_mfma_f32_16x16x32_bf16((a), (b), (c), 0, 0, 0)

__device__ __forceinline__ void gload_lds16(const void* g, void* l) {
  __builtin_amdgcn_global_load_lds(
      (const __attribute__((address_space(1))) unsigned int*)(uintptr_t)g,
      (__attribute__((address_space(3))) unsigned int*)(uintptr_t)l,
      16, 0, 0);
}

template <int N>
__device__ __forceinline__ void wait_vmcnt() {
  if constexpr (N == 0)      asm volatile("s_waitcnt vmcnt(0)" ::: "memory");
  else if constexpr (N == 3) asm volatile("s_waitcnt vmcnt(3)" ::: "memory");
  else if constexpr (N == 4) asm volatile("s_waitcnt vmcnt(4)" ::: "memory");
  else if constexpr (N == 6) asm volatile("s_waitcnt vmcnt(6)" ::: "memory");
  else                       asm volatile("s_waitcnt vmcnt(8)" ::: "memory");
}

// LDS 16B-chunk swizzle for K-contig tiles (BK=32): sc = cc ^ ((row>>1)&3)
__device__ __forceinline__ int swz32(int row) { return (row >> 1) & 3; }

// stage ROWS x 32 bf16 tile (row-major, ldg stride) into LDS, 256 threads
template <int ROWS>
__device__ __forceinline__ void stage_tile32(const bf16* __restrict__ g, int ldg,
                                             bf16* __restrict__ l, int t) {
  constexpr int ITER = ROWS * 32 / 2048;
#pragma unroll
  for (int i = 0; i < ITER; ++i) {
    const int off = (i * 256 + t) * 8;
    const int row = off >> 5;
    const int cc = (off & 31) >> 3;
    const int sc = cc ^ swz32(row);
    gload_lds16(&g[(size_t)row * ldg + (sc << 3)], &l[off]);
  }
}

// repack-LDS address: tile [128 rows][128 cols] bf16, 256B rows, 16B-chunk XOR swizzle
__device__ __forceinline__ int rpk(int row, int col) {
  return row * 256 + ((((col >> 3) ^ (row & 7)) << 4)) + ((col & 7) << 1);
}

// ---------------- fused prep: weight/activation casts + LN1, one dispatch ----------------
__global__ __launch_bounds__(256) void prep_kernel(
    const float* __restrict__ wq, const float* __restrict__ wk,
    const float* __restrict__ wv, const float* __restrict__ wo,
    const float* __restrict__ w1, const float* __restrict__ w2,
    const float* __restrict__ enc, const float* __restrict__ emb,
    const float* __restrict__ g1, const float* __restrict__ be1,
    bf16* __restrict__ wqkv_bf, bf16* __restrict__ wo_bf,
    bf16* __restrict__ w1_bf, bf16* __restrict__ w2_bf,
    bf16* __restrict__ enc_bf, bf16* __restrict__ qin_bf) {
  const int bid = blockIdx.x, t = threadIdx.x;
  if (bid < 16384) {
    const float* in;
    bf16* out;
    int idx;
    if (bid < 4096) {
      const int sel = bid >> 10;
      in = sel == 0 ? wq : sel == 1 ? wk : sel == 2 ? wv : wo;
      out = sel == 3 ? wo_bf : wqkv_bf + ((size_t)sel << 20);
      idx = (bid & 1023) * 256 + t;
    } else {
      const int sel = (bid - 4096) >> 12;
      in = sel == 0 ? w1 : sel == 1 ? w2 : enc;
      out = sel == 0 ? w1_bf : sel == 1 ? w2_bf : enc_bf;
      idx = ((bid - 4096) & 4095) * 256 + t;
    }
    const float4 v = ((const float4*)in)[idx];
    bf16x4 ov;
    ov[0] = (bf16)v.x; ov[1] = (bf16)v.y; ov[2] = (bf16)v.z; ov[3] = (bf16)v.w;
    ((bf16x4*)out)[idx] = ov;
    return;
  }
  // LayerNorm(emb) row
  const int row = bid - 16384;
  const float4 v = ((const float4*)(emb + (size_t)row * DM))[t];
  float s  = v.x + v.y + v.z + v.w;
  float s2 = v.x * v.x + v.y * v.y + v.z * v.z + v.w * v.w;
#pragma unroll
  for (int m = 1; m < 64; m <<= 1) { s += __shfl_xor(s, m); s2 += __shfl_xor(s2, m); }
  __shared__ float red[8];
  const int w = t >> 6;
  if ((t & 63) == 0) { red[w] = s; red[4 + w] = s2; }
  __syncthreads();
  s  = red[0] + red[1] + red[2] + red[3];
  s2 = red[4] + red[5] + red[6] + red[7];
  const float mean = s * (1.f / DM);
  const float var  = s2 * (1.f / DM) - mean * mean;
  const float rstd = rsqrtf(var + 1e-5f);
  const float4 g4 = ((const float4*)g1)[t];
  const float4 b4 = ((const float4*)be1)[t];
  bf16x4 ov;
  ov[0] = (bf16)((v.x - mean) * rstd * g4.x + b4.x);
  ov[1] = (bf16)((v.y - mean) * rstd * g4.y + b4.y);
  ov[2] = (bf16)((v.z - mean) * rstd * g4.z + b4.z);
  ov[3] = (bf16)((v.w - mean) * rstd * g4.w + b4.w);
  ((bf16x4*)(qin_bf + (size_t)row * DM))[t] = ov;
}

// ---------------- LayerNorm (f32 in, bf16 out) ----------------
__global__ __launch_bounds__(256) void ln_kernel(const float* __restrict__ x,
                                                 const float* __restrict__ gam,
                                                 const float* __restrict__ bet,
                                                 bf16* __restrict__ out) {
  const int row = blockIdx.x, t = threadIdx.x;
  const float4 v = ((const float4*)(x + (size_t)row * DM))[t];
  float s  = v.x + v.y + v.z + v.w;
  float s2 = v.x * v.x + v.y * v.y + v.z * v.z + v.w * v.w;
#pragma unroll
  for (int m = 1; m < 64; m <<= 1) { s += __shfl_xor(s, m); s2 += __shfl_xor(s2, m); }
  __shared__ float red[8];
  const int w = t >> 6;
  if ((t & 63) == 0) { red[w] = s; red[4 + w] = s2; }
  __syncthreads();
  s  = red[0] + red[1] + red[2] + red[3];
  s2 = red[4] + red[5] + red[6] + red[7];
  const float mean = s * (1.f / DM);
  const float var  = s2 * (1.f / DM) - mean * mean;
  const float rstd = rsqrtf(var + 1e-5f);
  const float4 g4 = ((const float4*)gam)[t];
  const float4 b4 = ((const float4*)bet)[t];
  bf16x4 ov;
  ov[0] = (bf16)((v.x - mean) * rstd * g4.x + b4.x);
  ov[1] = (bf16)((v.y - mean) * rstd * g4.y + b4.y);
  ov[2] = (bf16)((v.z - mean) * rstd * g4.z + b4.z);
  ov[3] = (bf16)((v.w - mean) * rstd * g4.w + b4.w);
  ((bf16x4*)(out + (size_t)row * DM))[t] = ov;
}

// ---------------- bf16 MFMA GEMM v3: depth-2 counted-vmcnt pipeline ----------------
enum { EPI_QKV = 0, EPI_O = 3, EPI_F1 = 4, EPI_F2 = 5 };

struct GParams {
  const bf16* A;    // A operand (M x K, K-contig)
  const bf16* A2;   // QKV: A for n0 >= 1024 (enc)
  const bf16* W;    // weights (N x K, K-contig)
  const float* b0;  // bias (QKV: bq)
  const float* b1;  // QKV: bk
  const float* b2;  // QKV: bv
  const float* resid;
  void* out;        // QKV: Q
  void* out1;       // QKV: K
  void* out2;       // QKV: V^T
  int N;
  int K;
};

template <int MODE, int BN, int MINB>
__global__ __launch_bounds__(256, MINB) void gemm3(GParams p) {
  constexpr int BM = 128, BK = 32;
  constexpr int WTM = (BN == 128) ? 64 : 32;  // wave tile rows
  constexpr int MI = WTM / 16;
  constexpr int L = 2 + BN * BK / 2048;       // loads per tile per thread (A + B)
  __shared__ __align__(16) bf16 As[4][BM * BK];
  __shared__ __align__(16) bf16 Bs[4][BN * BK];
  const int t = threadIdx.x, lane = t & 63, w = t >> 6;
  const int lr = lane & 15, lg = lane >> 4;
  const int wr = (BN == 128) ? (w >> 1) : w;
  const int wc = (BN == 128) ? (w & 1) : 0;
  const int m0 = blockIdx.x * BM, n0 = blockIdx.y * BN;
  const bf16* Ap = (MODE == EPI_QKV && n0 >= 1024) ? p.A2 : p.A;
  const bf16* Wp = &p.W[(size_t)n0 * p.K];
  const bf16* Arow = &Ap[(size_t)m0 * p.K];
  const f32x4 FZ = {0.f, 0.f, 0.f, 0.f};
  f32x4 acc[MI][4];
#pragma unroll
  for (int i = 0; i < MI; ++i)
#pragma unroll
    for (int j = 0; j < 4; ++j) acc[i][j] = FZ;

  const int nk = p.K / BK;
  // prologue: stage tiles 0 and 1
  stage_tile32<BM>(Arow, p.K, As[0], t);
  stage_tile32<BN>(Wp, p.K, Bs[0], t);
  stage_tile32<BM>(Arow + BK, p.K, As[1], t);
  stage_tile32<BN>(Wp + BK, p.K, Bs[1], t);

  for (int kt = 0; kt < nk; ++kt) {
    if (kt + 2 < nk) {
      stage_tile32<BM>(Arow + (size_t)(kt + 2) * BK, p.K, As[(kt + 2) & 3], t);
      stage_tile32<BN>(Wp + (size_t)(kt + 2) * BK, p.K, Bs[(kt + 2) & 3], t);
      wait_vmcnt<2 * L>();
    } else if (kt + 1 < nk) {
      wait_vmcnt<L>();
    } else {
      wait_vmcnt<0>();
    }
    __builtin_amdgcn_s_barrier();

    const bf16* Asl = As[kt & 3];
    const bf16* Bsl = Bs[kt & 3];
    bf16x8 af[MI], bfr[4];
#pragma unroll
    for (int i = 0; i < MI; ++i) {
      const int row = wr * WTM + i * 16 + lr;
      af[i] = *(const bf16x8*)&Asl[row * BK + ((lg ^ swz32(row)) << 3)];
    }
#pragma unroll
    for (int j = 0; j < 4; ++j) {
      const int row = wc * 64 + j * 16 + lr;
      bfr[j] = *(const bf16x8*)&Bsl[row * BK + ((lg ^ swz32(row)) << 3)];
    }
    __builtin_amdgcn_s_setprio(1);
#pragma unroll
    for (int i = 0; i < MI; ++i)
#pragma unroll
      for (int j = 0; j < 4; ++j) acc[i][j] = MFMA16(af[i], bfr[j], acc[i][j]);
    __builtin_amdgcn_s_setprio(0);
  }

  if constexpr (BN == 64) {
    // direct f32 epilogue (full 64B-line stores): O / F2
#pragma unroll
    for (int i = 0; i < MI; ++i) {
#pragma unroll
      for (int j = 0; j < 4; ++j) {
        const int c = n0 + j * 16 + lr;
        const float bj = p.b0[c];
#pragma unroll
        for (int g = 0; g < 4; ++g) {
          const int r = m0 + wr * WTM + i * 16 + 4 * lg + g;
          const size_t idx = (size_t)r * p.N + c;
          ((float*)p.out)[idx] = acc[i][j][g] + bj + p.resid[idx];
        }
      }
    }
    return;
  }

  // ---- LDS-repack epilogue (BN == 128): QKV / F1 ----
  bf16* R = &As[0][0];  // 32 KB: [128 rows][256 B], chunk-XOR swizzled
  __syncthreads();      // all compute reads of As/Bs done
#pragma unroll
  for (int i = 0; i < MI; ++i) {
#pragma unroll
    for (int j = 0; j < 4; ++j) {
      const int col = wc * 64 + j * 16 + lr;
      const int c = n0 + col;
      float bj;
      if constexpr (MODE == EPI_QKV)
        bj = (c < 1024 ? p.b0 : c < 2048 ? p.b1 : p.b2)[c & 1023];
      else
        bj = p.b0[c];
#pragma unroll
      for (int g = 0; g < 4; ++g) {
        const int row = wr * 64 + i * 16 + 4 * lg + g;
        float v = acc[i][j][g] + bj;
        if constexpr (MODE == EPI_QKV) {
          if (c < 1024) v *= 0.125f;  // fold 1/sqrt(dk) into Q
        } else {
          v = fmaxf(v, 0.f);  // F1 relu
        }
        *(bf16*)((char*)R + rpk(row, col)) = (bf16)v;
      }
    }
  }
  __syncthreads();

  if constexpr (MODE == EPI_F1) {
    // out row-major [4096][4096] bf16, 16B/lane coalesced
#pragma unroll
    for (int q = 0; q < 8; ++q) {
      const int idx = q * 256 + t;
      const int r = idx >> 4, cc = idx & 15;
      const bf16x8 vv = *(const bf16x8*)((char*)R + r * 256 + (((cc ^ (r & 7)) << 4)));
      *(bf16x8*)&((bf16*)p.out)[(size_t)(m0 + r) * p.N + n0 + cc * 8] = vv;
    }
  } else {
    const int l0 = m0 >> 2;
    const int h0 = (n0 & 1023) >> 6;
    if (n0 < 2048) {
      // Q or K: out[(bh, l, d)], 16B/lane
      bf16* outp = (bf16*)(n0 < 1024 ? p.out : p.out1);
#pragma unroll
      for (int q = 0; q < 8; ++q) {
        const int b = q >> 1, hsel = q & 1;
        const int l = t >> 3, cc = t & 7;
        const int row = l * 4 + b;
        const int ccl = hsel * 8 + cc;
        const bf16x8 vv = *(const bf16x8*)((char*)R + row * 256 + (((ccl ^ (row & 7)) << 4)));
        const int bh = b * NH + h0 + hsel;
        *(bf16x8*)&outp[(((size_t)bh << 10) + l0 + l) * DKH + cc * 8] = vv;
      }
    } else {
      // V^T: out2[(bh, d, kv)], gather 8 kv per lane -> 16B stores
      bf16* outp = (bf16*)p.out2;
#pragma unroll
      for (int q = 0; q < 8; ++q) {
        const int idx = q * 256 + t;
        const int rs = idx >> 2, kc = idx & 3;
        const int b = rs >> 7, hsel = (rs >> 6) & 1, d = rs & 63;
        const int col = hsel * 64 + d;
        bf16x8 vv;
#pragma unroll
        for (int e = 0; e < 8; ++e) {
          const int row = (kc * 8 + e) * 4 + b;
          vv[e] = *(const bf16*)((char*)R + rpk(row, col));
        }
        const int bh = b * NH + h0 + hsel;
        *(bf16x8*)&outp[(((size_t)bh * DKH + d) << 10) + l0 + kc * 8] = vv;
      }
    }
  }
}

// ---------------- flash attention (unchanged from round 4) ----------------
__global__ __launch_bounds__(512, 4) void attn_kernel(const bf16* __restrict__ Qg,
                                                      const bf16* __restrict__ Kg,
                                                      const bf16* __restrict__ Vtg,
                                                      const unsigned char* __restrict__ smask,
                                                      bf16* __restrict__ Og) {
  __shared__ __align__(16) bf16 Ks[2][4096];
  __shared__ __align__(16) bf16 Vs[2][4096];
  __shared__ __align__(16) bf16 Ps[8][1152];
  const int t = threadIdx.x, lane = t & 63, w = t >> 6;
  const int lr = lane & 15, lg = lane >> 4;
  const int id = blockIdx.x;
  const int bh = ((id >> 6) << 3) | (id & 7);
  const int qt = (id >> 3) & 7;
  const int b = bh >> 4, h = bh & 15;
  const int q0 = qt * 128 + w * 16;
  const size_t base = (size_t)bh << 16;

  bf16x8 qa[2];
#pragma unroll
  for (int c = 0; c < 2; ++c)
    qa[c] = *(const bf16x8*)&Qg[base + (size_t)(q0 + lr) * DKH + c * 32 + lg * 8];

  const f32x4 FZ = {0.f, 0.f, 0.f, 0.f};
  f32x4 o[4];
  float mrun[4], lrun[4];
#pragma unroll
  for (int g = 0; g < 4; ++g) { mrun[g] = -INFINITY; lrun[g] = 0.f; o[g] = FZ; }

  const int soff = t * 8;
  const int shi = soff >> 11, smid = (soff >> 5) & 63;
  const int ssc = (((soff >> 3) & 3) ^ ((smid >> 1) & 3)) << 3;

  gload_lds16(&Kg[base + (size_t)smid * DKH + shi * 32 + ssc], &Ks[0][soff]);
  gload_lds16(&Vtg[base + (size_t)smid * SEQ + shi * 32 + ssc], &Vs[0][soff]);
  asm volatile("s_waitcnt vmcnt(0)" ::: "memory");
  __syncthreads();

  const int rsw = ((lr >> 1) & 3);

  int cur = 0;
  for (int kt = 0; kt < SEQ / 64; ++kt) {
    const int kv0 = kt * 64;
    if (kt + 1 < SEQ / 64) {
      gload_lds16(&Kg[base + (size_t)(kv0 + 64 + smid) * DKH + shi * 32 + ssc], &Ks[cur ^ 1][soff]);
      gload_lds16(&Vtg[base + (size_t)smid * SEQ + kv0 + 64 + shi * 32 + ssc], &Vs[cur ^ 1][soff]);
    }

    f32x4 s[4];
#pragma unroll
    for (int n = 0; n < 4; ++n) s[n] = FZ;
#pragma unroll
    for (int c = 0; c < 2; ++c) {
      bf16x8 kb[4];
#pragma unroll
      for (int n = 0; n < 4; ++n)
        kb[n] = *(const bf16x8*)&Ks[cur][c * 2048 + (n * 16 + lr) * 32 + ((lg ^ rsw) << 3)];
      __builtin_amdgcn_s_setprio(1);
#pragma unroll
      for (int n = 0; n < 4; ++n) s[n] = MFMA16(qa[c], kb[n], s[n]);
      __builtin_amdgcn_s_setprio(0);
    }

    float madd[4];
#pragma unroll
    for (int n = 0; n < 4; ++n)
      madd[n] = smask[(size_t)(kv0 + n * 16 + lr) * NB + b] ? -1e10f : 0.f;
#pragma unroll
    for (int n = 0; n < 4; ++n)
#pragma unroll
      for (int g = 0; g < 4; ++g) s[n][g] += madd[n];

    float tm4[4];
    bool needany = false;
#pragma unroll
    for (int g = 0; g < 4; ++g) {
      float tm = fmaxf(fmaxf(s[0][g], s[1][g]), fmaxf(s[2][g], s[3][g]));
      tm = fmaxf(tm, __shfl_xor(tm, 1));
      tm = fmaxf(tm, __shfl_xor(tm, 2));
      tm = fmaxf(tm, __shfl_xor(tm, 4));
      tm = fmaxf(tm, __shfl_xor(tm, 8));
      tm4[g] = tm;
      needany |= (tm > mrun[g] + 8.f);
    }
    if (__any(needany)) {
#pragma unroll
      for (int g = 0; g < 4; ++g) {
        const float mnew = fmaxf(mrun[g], tm4[g]);
        const float sc = __expf(mrun[g] - mnew);
        mrun[g] = mnew;
        lrun[g] *= sc;
#pragma unroll
        for (int n = 0; n < 4; ++n) o[n][g] *= sc;
      }
    }
#pragma unroll
    for (int g = 0; g < 4; ++g) {
      float ts = 0.f;
#pragma unroll
      for (int n = 0; n < 4; ++n) {
        const float p = __expf(s[n][g] - mrun[g]);
        s[n][g] = p;
        ts += p;
      }
      ts += __shfl_xor(ts, 1);
      ts += __shfl_xor(ts, 2);
      ts += __shfl_xor(ts, 4);
      ts += __shfl_xor(ts, 8);
      lrun[g] += ts;
    }

    bf16* Pw = &Ps[w][0];
#pragma unroll
    for (int n = 0; n < 4; ++n)
#pragma unroll
      for (int g = 0; g < 4; ++g)
        Pw[(4 * lg + g) * 72 + n * 16 + lr] = (bf16)s[n][g];
    __builtin_amdgcn_sched_barrier(0);

#pragma unroll
    for (int c = 0; c < 2; ++c) {
      const bf16x8 pa = *(const bf16x8*)&Pw[lr * 72 + c * 32 + lg * 8];
      bf16x8 vb[4];
#pragma unroll
      for (int n = 0; n < 4; ++n)
        vb[n] = *(const bf16x8*)&Vs[cur][c * 2048 + (n * 16 + lr) * 32 + ((lg ^ rsw) << 3)];
      __builtin_amdgcn_s_setprio(1);
#pragma unroll
      for (int n = 0; n < 4; ++n) o[n] = MFMA16(pa, vb[n], o[n]);
      __builtin_amdgcn_s_setprio(0);
    }

    asm volatile("s_waitcnt vmcnt(0)" ::: "memory");
    __syncthreads();
    cur ^= 1;
  }

#pragma unroll
  for (int g = 0; g < 4; ++g) {
    const int l = q0 + 4 * lg + g;
    const float inv = 1.0f / lrun[g];
#pragma unroll
    for (int n = 0; n < 4; ++n)
      Og[(size_t)(l * NB + b) * DM + h * 64 + n * 16 + lr] = (bf16)(o[n][g] * inv);
  }
}

// ---------------- host orchestration ----------------
extern "C" void kernel_launch(void* const* d_in, const int* in_sizes, int n_in,
                              void* d_out, int out_size, void* d_ws, size_t ws_size,
                              hipStream_t stream) {
  const float* enc = (const float*)d_in[0];
  const float* emb = (const float*)d_in[1];
  const unsigned char* smask = (const unsigned char*)d_in[2];
  const float* wq = (const float*)d_in[12]; const float* bq = (const float*)d_in[13];
  const float* wk = (const float*)d_in[14]; const float* bk = (const float*)d_in[15];
  const float* wv = (const float*)d_in[16]; const float* bv = (const float*)d_in[17];
  const float* wo = (const float*)d_in[18]; const float* bo = (const float*)d_in[19];
  const float* w1 = (const float*)d_in[20]; const float* b1 = (const float*)d_in[21];
  const float* w2 = (const float*)d_in[22]; const float* b2 = (const float*)d_in[23];
  const float* g1 = (const float*)d_in[26]; const float* be1 = (const float*)d_in[27];
  const float* g2 = (const float*)d_in[28]; const float* be2 = (const float*)d_in[29];

  char* ws = (char*)d_ws;
  const size_t MB = (size_t)1 << 20;
  bf16* wqkv_bf = (bf16*)(ws + 0 * MB);   // 3072x1024 packed (Q|K|V)
  bf16* wo_bf   = (bf16*)(ws + 6 * MB);
  bf16* w1_bf   = (bf16*)(ws + 8 * MB);
  bf16* w2_bf   = (bf16*)(ws + 16 * MB);
  bf16* enc_bf  = (bf16*)(ws + 24 * MB);
  bf16* z_bf    = enc_bf;                 // alias: enc_bf dead after QKV proj
  bf16* qin_bf  = (bf16*)(ws + 32 * MB);
  bf16* attn_bf = qin_bf;                 // alias: qin dead after QKV proj
  bf16* Q_bf    = (bf16*)(ws + 40 * MB);
  bf16* K_bf    = (bf16*)(ws + 48 * MB);
  bf16* Vt_bf   = (bf16*)(ws + 56 * MB);
  float* encdec = (float*)(ws + 64 * MB);
  bf16* h_bf    = (bf16*)(ws + 80 * MB);

  // fused casts + LN1 (one dispatch)
  prep_kernel<<<20480, 256, 0, stream>>>(wq, wk, wv, wo, w1, w2, enc, emb, g1, be1,
                                         wqkv_bf, wo_bf, w1_bf, w2_bf, enc_bf, qin_bf);

  // fused Q|K|V projection: N=3072
  {
    GParams p{qin_bf, enc_bf, wqkv_bf, bq, bk, bv, nullptr, Q_bf, K_bf, Vt_bf, 3072, DM};
    gemm3<EPI_QKV, 128, 2><<<dim3(32, 24), 256, 0, stream>>>(p);
  }

  // flash attention: 512 blocks x 512 threads (XCD-swizzled 1-D grid)
  attn_kernel<<<512, 512, 0, stream>>>(Q_bf, K_bf, Vt_bf, smask, attn_bf);

  // O projection + residual(embedded) -> enc_dec (f32)
  {
    GParams p{attn_bf, nullptr, wo_bf, bo, nullptr, nullptr, emb, encdec, nullptr, nullptr, DM, DM};
    gemm3<EPI_O, 64, 3><<<dim3(32, 16), 256, 0, stream>>>(p);
  }

  // LN2(enc_dec) -> z
  ln_kernel<<<4096, 256, 0, stream>>>(encdec, g2, be2, z_bf);

  // FFN
  {
    GParams p{z_bf, nullptr, w1_bf, b1, nullptr, nullptr, nullptr, h_bf, nullptr, nullptr, DF, DM};
    gemm3<EPI_F1, 128, 2><<<dim3(32, 32), 256, 0, stream>>>(p);
  }
  {
    GParams p{h_bf, nullptr, w2_bf, b2, nullptr, nullptr, encdec, d_out, nullptr, nullptr, DM, DF};
    gemm3<EPI_F2, 64, 3><<<dim3(32, 16), 256, 0, stream>>>(p);
  }
}

// Round 6
// 370.952 us; speedup vs baseline: 1.0669x; 1.0669x over previous
//
#include <hip/hip_runtime.h>
#include <cstdint>
#include <math.h>

// Problem constants
constexpr int NH  = 16;    // heads
constexpr int DKH = 64;    // head dim
constexpr int SEQ = 1024;  // LT == LS
constexpr int NB  = 4;     // batch
constexpr int DM  = 1024;  // d_model
constexpr int DF  = 4096;  // ffn dim

typedef __bf16 bf16;
typedef __bf16 bf16x4 __attribute__((ext_vector_type(4)));
typedef __bf16 bf16x8 __attribute__((ext_vector_type(8)));
typedef float  f32x4  __attribute__((ext_vector_type(4)));

#define MFMA16(a, b, c) __builtin_amdgcn_mfma_f32_16x16x32_bf16((a), (b), (c), 0, 0, 0)

__device__ __forceinline__ void gload_lds16(const void* g, void* l) {
  __builtin_amdgcn_global_load_lds(
      (const __attribute__((address_space(1))) unsigned int*)(uintptr_t)g,
      (__attribute__((address_space(3))) unsigned int*)(uintptr_t)l,
      16, 0, 0);
}

template <int N>
__device__ __forceinline__ void wait_vmcnt() {
  if constexpr (N == 0)      asm volatile("s_waitcnt vmcnt(0)" ::: "memory");
  else if constexpr (N == 6) asm volatile("s_waitcnt vmcnt(6)" ::: "memory");
  else                       asm volatile("s_waitcnt vmcnt(12)" ::: "memory");
}

// stage R x 64 bf16 tile (row 128B = 8 chunks of 16B) into LDS, 512 threads.
// Chunk-XOR swizzle: LDS chunk cc of row holds global chunk cc^(row&7).
// (global source pre-swizzled, LDS dest linear -> rule #21 safe)
template <int R>
__device__ __forceinline__ void stage64(const bf16* __restrict__ g, int ldg,
                                        bf16* __restrict__ l, int t) {
#pragma unroll
  for (int i = 0; i < R / 64; ++i) {
    const int off = (i * 512 + t) * 16;  // byte offset
    const int row = off >> 7;
    const int cc = (off >> 4) & 7;
    const int sc = cc ^ (row & 7);
    gload_lds16(&g[(size_t)row * ldg + sc * 8], (char*)l + off);
  }
}

// repack-LDS byte address: [256 rows][128 cols] bf16, 256B rows, 16B-chunk XOR
__device__ __forceinline__ int rpk(int row, int col) {
  return row * 256 + (((col >> 3) ^ (row & 7)) << 4) + ((col & 7) << 1);
}

// ---------------- fused prep: weight/activation casts + LN1, one dispatch ----------------
__global__ __launch_bounds__(256) void prep_kernel(
    const float* __restrict__ wq, const float* __restrict__ wk,
    const float* __restrict__ wv, const float* __restrict__ wo,
    const float* __restrict__ w1, const float* __restrict__ w2,
    const float* __restrict__ enc, const float* __restrict__ emb,
    const float* __restrict__ g1, const float* __restrict__ be1,
    bf16* __restrict__ wqkv_bf, bf16* __restrict__ wo_bf,
    bf16* __restrict__ w1_bf, bf16* __restrict__ w2_bf,
    bf16* __restrict__ enc_bf, bf16* __restrict__ qin_bf) {
  const int bid = blockIdx.x, t = threadIdx.x;
  if (bid < 16384) {
    const float* in;
    bf16* out;
    int idx;
    if (bid < 4096) {
      const int sel = bid >> 10;
      in = sel == 0 ? wq : sel == 1 ? wk : sel == 2 ? wv : wo;
      out = sel == 3 ? wo_bf : wqkv_bf + ((size_t)sel << 20);
      idx = (bid & 1023) * 256 + t;
    } else {
      const int sel = (bid - 4096) >> 12;
      in = sel == 0 ? w1 : sel == 1 ? w2 : enc;
      out = sel == 0 ? w1_bf : sel == 1 ? w2_bf : enc_bf;
      idx = ((bid - 4096) & 4095) * 256 + t;
    }
    const float4 v = ((const float4*)in)[idx];
    bf16x4 ov;
    ov[0] = (bf16)v.x; ov[1] = (bf16)v.y; ov[2] = (bf16)v.z; ov[3] = (bf16)v.w;
    ((bf16x4*)out)[idx] = ov;
    return;
  }
  // LayerNorm(emb) row
  const int row = bid - 16384;
  const float4 v = ((const float4*)(emb + (size_t)row * DM))[t];
  float s  = v.x + v.y + v.z + v.w;
  float s2 = v.x * v.x + v.y * v.y + v.z * v.z + v.w * v.w;
#pragma unroll
  for (int m = 1; m < 64; m <<= 1) { s += __shfl_xor(s, m); s2 += __shfl_xor(s2, m); }
  __shared__ float red[8];
  const int w = t >> 6;
  if ((t & 63) == 0) { red[w] = s; red[4 + w] = s2; }
  __syncthreads();
  s  = red[0] + red[1] + red[2] + red[3];
  s2 = red[4] + red[5] + red[6] + red[7];
  const float mean = s * (1.f / DM);
  const float var  = s2 * (1.f / DM) - mean * mean;
  const float rstd = rsqrtf(var + 1e-5f);
  const float4 g4 = ((const float4*)g1)[t];
  const float4 b4 = ((const float4*)be1)[t];
  bf16x4 ov;
  ov[0] = (bf16)((v.x - mean) * rstd * g4.x + b4.x);
  ov[1] = (bf16)((v.y - mean) * rstd * g4.y + b4.y);
  ov[2] = (bf16)((v.z - mean) * rstd * g4.z + b4.z);
  ov[3] = (bf16)((v.w - mean) * rstd * g4.w + b4.w);
  ((bf16x4*)(qin_bf + (size_t)row * DM))[t] = ov;
}

// ---------------- LN2 fused with O-combine: encdec = Po0+Po1+bo+emb; z = LN(encdec) ----------------
__global__ __launch_bounds__(256) void ln2_kernel(const float* __restrict__ P0,
                                                  const float* __restrict__ P1,
                                                  const float* __restrict__ bo,
                                                  const float* __restrict__ emb,
                                                  const float* __restrict__ gam,
                                                  const float* __restrict__ bet,
                                                  float* __restrict__ encdec,
                                                  bf16* __restrict__ z) {
  const int row = blockIdx.x, t = threadIdx.x;
  const float4 p0 = ((const float4*)(P0 + (size_t)row * DM))[t];
  const float4 p1 = ((const float4*)(P1 + (size_t)row * DM))[t];
  const float4 e4 = ((const float4*)(emb + (size_t)row * DM))[t];
  const float4 bb = ((const float4*)bo)[t];
  float4 v;
  v.x = p0.x + p1.x + bb.x + e4.x;
  v.y = p0.y + p1.y + bb.y + e4.y;
  v.z = p0.z + p1.z + bb.z + e4.z;
  v.w = p0.w + p1.w + bb.w + e4.w;
  ((float4*)(encdec + (size_t)row * DM))[t] = v;
  float s  = v.x + v.y + v.z + v.w;
  float s2 = v.x * v.x + v.y * v.y + v.z * v.z + v.w * v.w;
#pragma unroll
  for (int m = 1; m < 64; m <<= 1) { s += __shfl_xor(s, m); s2 += __shfl_xor(s2, m); }
  __shared__ float red[8];
  const int w = t >> 6;
  if ((t & 63) == 0) { red[w] = s; red[4 + w] = s2; }
  __syncthreads();
  s  = red[0] + red[1] + red[2] + red[3];
  s2 = red[4] + red[5] + red[6] + red[7];
  const float mean = s * (1.f / DM);
  const float var  = s2 * (1.f / DM) - mean * mean;
  const float rstd = rsqrtf(var + 1e-5f);
  const float4 g4 = ((const float4*)gam)[t];
  const float4 b4 = ((const float4*)bet)[t];
  bf16x4 ov;
  ov[0] = (bf16)((v.x - mean) * rstd * g4.x + b4.x);
  ov[1] = (bf16)((v.y - mean) * rstd * g4.y + b4.y);
  ov[2] = (bf16)((v.z - mean) * rstd * g4.z + b4.z);
  ov[3] = (bf16)((v.w - mean) * rstd * g4.w + b4.w);
  ((bf16x4*)(z + (size_t)row * DM))[t] = ov;
}

// ---------------- final combine: d_out = Pf0+Pf1+b2+encdec ----------------
__global__ __launch_bounds__(256) void fin_kernel(const float* __restrict__ P0,
                                                  const float* __restrict__ P1,
                                                  const float* __restrict__ b2,
                                                  const float* __restrict__ encdec,
                                                  float* __restrict__ out) {
  const int idx = blockIdx.x * 256 + threadIdx.x;  // float4 index
  const float4 p0 = ((const float4*)P0)[idx];
  const float4 p1 = ((const float4*)P1)[idx];
  const float4 e4 = ((const float4*)encdec)[idx];
  const float4 bb = ((const float4*)b2)[idx & 255];
  float4 v;
  v.x = p0.x + p1.x + bb.x + e4.x;
  v.y = p0.y + p1.y + bb.y + e4.y;
  v.z = p0.z + p1.z + bb.z + e4.z;
  v.w = p0.w + p1.w + bb.w + e4.w;
  ((float4*)out)[idx] = v;
}

// ---------------- GEMM v4: 256x128 tile, BK=64, 8 waves of 64x64, 3-buf 1-barrier counted-vmcnt ----------------
enum { G_QKV = 0, G_F1 = 1, G_PART = 2 };

struct GP {
  const bf16* A;    // A operand (M x K, K-contig)
  const bf16* A2;   // QKV: A for n0 >= 1024 (enc)
  const bf16* W;    // weights (N x K, K-contig)
  const float* b0;  // bias (QKV: bq)
  const float* b1;  // QKV: bk
  const float* b2;  // QKV: bv
  void* out;        // QKV: Q
  void* out1;       // QKV: K
  void* out2;       // QKV: V^T
  int N;            // output cols
  int K;            // full K (row stride)
  int Ksl;          // K per z-slice
};

template <int MODE>
__global__ __launch_bounds__(512, 1) void gemm4(GP p) {
  constexpr int BM = 256, BN = 128, BK = 64;
  __shared__ __align__(16) bf16 As[3][BM * BK];  // 96 KB
  __shared__ __align__(16) bf16 Bs[3][BN * BK];  // 48 KB  (total 144 KB)
  const int t = threadIdx.x, lane = t & 63, w = t >> 6;
  const int lr = lane & 15, lg = lane >> 4;
  const int wr = w >> 1, wc = w & 1;  // 4m x 2n waves, wave tile 64x64
  const int m0 = blockIdx.x * BM, n0 = blockIdx.y * BN;
  const bf16* Ap = (MODE == G_QKV && n0 >= 1024) ? p.A2 : p.A;
  const bf16* Arow = Ap + (size_t)m0 * p.K + (size_t)blockIdx.z * p.Ksl;
  const bf16* Wrow = p.W + (size_t)n0 * p.K + (size_t)blockIdx.z * p.Ksl;
  const f32x4 FZ = {0.f, 0.f, 0.f, 0.f};
  f32x4 acc[4][4];
#pragma unroll
  for (int i = 0; i < 4; ++i)
#pragma unroll
    for (int j = 0; j < 4; ++j) acc[i][j] = FZ;

  const int nk = p.Ksl / BK;
  stage64<BM>(Arow, p.K, As[0], t);  // 4 loads
  stage64<BN>(Wrow, p.K, Bs[0], t);  // 2 loads

  int bi = 0;
  for (int kt = 0; kt < nk; ++kt) {
    int si = bi + 1; if (si == 3) si = 0;
    if (kt + 1 < nk) {
      stage64<BM>(Arow + (size_t)(kt + 1) * BK, p.K, As[si], t);
      stage64<BN>(Wrow + (size_t)(kt + 1) * BK, p.K, Bs[si], t);
      wait_vmcnt<6>();   // own tile-kt loads done; tile kt+1's 6 stay in flight
    } else {
      wait_vmcnt<0>();
    }
    __builtin_amdgcn_s_barrier();

    const bf16* Asl = As[bi];
    const bf16* Bsl = Bs[bi];
#pragma unroll
    for (int kh = 0; kh < 2; ++kh) {
      bf16x8 af[4], bfr[4];
#pragma unroll
      for (int i = 0; i < 4; ++i) {
        const int row = wr * 64 + i * 16 + lr;
        af[i] = *(const bf16x8*)((const char*)Asl + row * 128 + ((((kh * 4 + lg) ^ (row & 7))) << 4));
      }
#pragma unroll
      for (int j = 0; j < 4; ++j) {
        const int row = wc * 64 + j * 16 + lr;
        bfr[j] = *(const bf16x8*)((const char*)Bsl + row * 128 + ((((kh * 4 + lg) ^ (row & 7))) << 4));
      }
      __builtin_amdgcn_s_setprio(1);
#pragma unroll
      for (int i = 0; i < 4; ++i)
#pragma unroll
        for (int j = 0; j < 4; ++j) acc[i][j] = MFMA16(af[i], bfr[j], acc[i][j]);
      __builtin_amdgcn_s_setprio(0);
    }
    bi = si;
  }

  // ---- epilogue ----
  if constexpr (MODE == G_PART) {
    float* Op = (float*)p.out + (size_t)blockIdx.z * ((size_t)4096 * p.N);
#pragma unroll
    for (int i = 0; i < 4; ++i)
#pragma unroll
      for (int j = 0; j < 4; ++j) {
        const int c = n0 + wc * 64 + j * 16 + lr;
#pragma unroll
        for (int g = 0; g < 4; ++g) {
          const int r = m0 + wr * 64 + i * 16 + 4 * lg + g;
          Op[(size_t)r * p.N + c] = acc[i][j][g];
        }
      }
    return;
  }

  // repack 256x128 result into LDS (64 KB over As[0..1]) then coalesced 16B stores
  bf16* R = As[0];
  __syncthreads();
#pragma unroll
  for (int i = 0; i < 4; ++i)
#pragma unroll
    for (int j = 0; j < 4; ++j) {
      const int cl = wc * 64 + j * 16 + lr;
      const int c = n0 + cl;
      float bj;
      if constexpr (MODE == G_QKV)
        bj = (c < 1024 ? p.b0 : c < 2048 ? p.b1 : p.b2)[c & 1023];
      else
        bj = p.b0[c];
#pragma unroll
      for (int g = 0; g < 4; ++g) {
        const int rl = wr * 64 + i * 16 + 4 * lg + g;
        float v = acc[i][j][g] + bj;
        if constexpr (MODE == G_QKV) {
          if (c < 1024) v *= 0.125f;  // fold 1/sqrt(dk) into Q
        } else {
          v = fmaxf(v, 0.f);  // F1 relu
        }
        *(bf16*)((char*)R + rpk(rl, cl)) = (bf16)v;
      }
    }
  __syncthreads();

  if constexpr (MODE == G_F1) {
    // h row-major [4096][4096] bf16
#pragma unroll
    for (int q = 0; q < 8; ++q) {
      const int idx = q * 512 + t;
      const int ch = idx & 15, row = idx >> 4;
      const bf16x8 vv = *(const bf16x8*)((char*)R + row * 256 + ((ch ^ (row & 7)) << 4));
      *(bf16x8*)&((bf16*)p.out)[(size_t)(m0 + row) * p.N + n0 + ch * 8] = vv;
    }
  } else {
    const int l0 = m0 >> 2;
    if (n0 < 2048) {
      // Q or K: (bh, l, d)
      bf16* outp = (bf16*)(n0 < 1024 ? p.out : p.out1);
      const int h0 = (n0 & 1023) >> 6;
#pragma unroll
      for (int q = 0; q < 8; ++q) {
        const int idx = q * 512 + t;
        const int dc = idx & 7, ll = (idx >> 3) & 63, b = (idx >> 9) & 3, hs = idx >> 11;
        const int row = ll * 4 + b, col = hs * 64 + dc * 8;
        const bf16x8 vv = *(const bf16x8*)((char*)R + row * 256 + ((((col >> 3) ^ (row & 7))) << 4));
        *(bf16x8*)&outp[((size_t)(b * NH + h0 + hs) * 1024 + l0 + ll) * 64 + dc * 8] = vv;
      }
    } else {
      // V^T: (bh, d, kv) — gather 8 kv per lane
      bf16* outp = (bf16*)p.out2;
      const int h0 = (n0 - 2048) >> 6;
#pragma unroll
      for (int q = 0; q < 8; ++q) {
        const int idx = q * 512 + t;
        const int kc = idx & 7, d = (idx >> 3) & 63, b = (idx >> 9) & 3, hs = idx >> 11;
        const int col = hs * 64 + d;
        bf16x8 vv;
#pragma unroll
        for (int e = 0; e < 8; ++e) {
          const int row = (kc * 8 + e) * 4 + b;
          vv[e] = *(const bf16*)((char*)R + rpk(row, col));
        }
        *(bf16x8*)&outp[((size_t)(b * NH + h0 + hs) * 64 + d) * 1024 + l0 + kc * 8] = vv;
      }
    }
  }
}

// ---------------- flash attention (unchanged from round 5) ----------------
__global__ __launch_bounds__(512, 4) void attn_kernel(const bf16* __restrict__ Qg,
                                                      const bf16* __restrict__ Kg,
                                                      const bf16* __restrict__ Vtg,
                                                      const unsigned char* __restrict__ smask,
                                                      bf16* __restrict__ Og) {
  __shared__ __align__(16) bf16 Ks[2][4096];
  __shared__ __align__(16) bf16 Vs[2][4096];
  __shared__ __align__(16) bf16 Ps[8][1152];
  const int t = threadIdx.x, lane = t & 63, w = t >> 6;
  const int lr = lane & 15, lg = lane >> 4;
  const int id = blockIdx.x;
  const int bh = ((id >> 6) << 3) | (id & 7);
  const int qt = (id >> 3) & 7;
  const int b = bh >> 4, h = bh & 15;
  const int q0 = qt * 128 + w * 16;
  const size_t base = (size_t)bh << 16;

  bf16x8 qa[2];
#pragma unroll
  for (int c = 0; c < 2; ++c)
    qa[c] = *(const bf16x8*)&Qg[base + (size_t)(q0 + lr) * DKH + c * 32 + lg * 8];

  const f32x4 FZ = {0.f, 0.f, 0.f, 0.f};
  f32x4 o[4];
  float mrun[4], lrun[4];
#pragma unroll
  for (int g = 0; g < 4; ++g) { mrun[g] = -INFINITY; lrun[g] = 0.f; o[g] = FZ; }

  const int soff = t * 8;
  const int shi = soff >> 11, smid = (soff >> 5) & 63;
  const int ssc = (((soff >> 3) & 3) ^ ((smid >> 1) & 3)) << 3;

  gload_lds16(&Kg[base + (size_t)smid * DKH + shi * 32 + ssc], &Ks[0][soff]);
  gload_lds16(&Vtg[base + (size_t)smid * SEQ + shi * 32 + ssc], &Vs[0][soff]);
  asm volatile("s_waitcnt vmcnt(0)" ::: "memory");
  __syncthreads();

  const int rsw = ((lr >> 1) & 3);

  int cur = 0;
  for (int kt = 0; kt < SEQ / 64; ++kt) {
    const int kv0 = kt * 64;
    if (kt + 1 < SEQ / 64) {
      gload_lds16(&Kg[base + (size_t)(kv0 + 64 + smid) * DKH + shi * 32 + ssc], &Ks[cur ^ 1][soff]);
      gload_lds16(&Vtg[base + (size_t)smid * SEQ + kv0 + 64 + shi * 32 + ssc], &Vs[cur ^ 1][soff]);
    }

    f32x4 s[4];
#pragma unroll
    for (int n = 0; n < 4; ++n) s[n] = FZ;
#pragma unroll
    for (int c = 0; c < 2; ++c) {
      bf16x8 kb[4];
#pragma unroll
      for (int n = 0; n < 4; ++n)
        kb[n] = *(const bf16x8*)&Ks[cur][c * 2048 + (n * 16 + lr) * 32 + ((lg ^ rsw) << 3)];
      __builtin_amdgcn_s_setprio(1);
#pragma unroll
      for (int n = 0; n < 4; ++n) s[n] = MFMA16(qa[c], kb[n], s[n]);
      __builtin_amdgcn_s_setprio(0);
    }

    float madd[4];
#pragma unroll
    for (int n = 0; n < 4; ++n)
      madd[n] = smask[(size_t)(kv0 + n * 16 + lr) * NB + b] ? -1e10f : 0.f;
#pragma unroll
    for (int n = 0; n < 4; ++n)
#pragma unroll
      for (int g = 0; g < 4; ++g) s[n][g] += madd[n];

    float tm4[4];
    bool needany = false;
#pragma unroll
    for (int g = 0; g < 4; ++g) {
      float tm = fmaxf(fmaxf(s[0][g], s[1][g]), fmaxf(s[2][g], s[3][g]));
      tm = fmaxf(tm, __shfl_xor(tm, 1));
      tm = fmaxf(tm, __shfl_xor(tm, 2));
      tm = fmaxf(tm, __shfl_xor(tm, 4));
      tm = fmaxf(tm, __shfl_xor(tm, 8));
      tm4[g] = tm;
      needany |= (tm > mrun[g] + 8.f);
    }
    if (__any(needany)) {
#pragma unroll
      for (int g = 0; g < 4; ++g) {
        const float mnew = fmaxf(mrun[g], tm4[g]);
        const float sc = __expf(mrun[g] - mnew);
        mrun[g] = mnew;
        lrun[g] *= sc;
#pragma unroll
        for (int n = 0; n < 4; ++n) o[n][g] *= sc;
      }
    }
#pragma unroll
    for (int g = 0; g < 4; ++g) {
      float ts = 0.f;
#pragma unroll
      for (int n = 0; n < 4; ++n) {
        const float p = __expf(s[n][g] - mrun[g]);
        s[n][g] = p;
        ts += p;
      }
      ts += __shfl_xor(ts, 1);
      ts += __shfl_xor(ts, 2);
      ts += __shfl_xor(ts, 4);
      ts += __shfl_xor(ts, 8);
      lrun[g] += ts;
    }

    bf16* Pw = &Ps[w][0];
#pragma unroll
    for (int n = 0; n < 4; ++n)
#pragma unroll
      for (int g = 0; g < 4; ++g)
        Pw[(4 * lg + g) * 72 + n * 16 + lr] = (bf16)s[n][g];
    __builtin_amdgcn_sched_barrier(0);

#pragma unroll
    for (int c = 0; c < 2; ++c) {
      const bf16x8 pa = *(const bf16x8*)&Pw[lr * 72 + c * 32 + lg * 8];
      bf16x8 vb[4];
#pragma unroll
      for (int n = 0; n < 4; ++n)
        vb[n] = *(const bf16x8*)&Vs[cur][c * 2048 + (n * 16 + lr) * 32 + ((lg ^ rsw) << 3)];
      __builtin_amdgcn_s_setprio(1);
#pragma unroll
      for (int n = 0; n < 4; ++n) o[n] = MFMA16(pa, vb[n], o[n]);
      __builtin_amdgcn_s_setprio(0);
    }

    asm volatile("s_waitcnt vmcnt(0)" ::: "memory");
    __syncthreads();
    cur ^= 1;
  }

#pragma unroll
  for (int g = 0; g < 4; ++g) {
    const int l = q0 + 4 * lg + g;
    const float inv = 1.0f / lrun[g];
#pragma unroll
    for (int n = 0; n < 4; ++n)
      Og[(size_t)(l * NB + b) * DM + h * 64 + n * 16 + lr] = (bf16)(o[n][g] * inv);
  }
}

// ---------------- host orchestration ----------------
extern "C" void kernel_launch(void* const* d_in, const int* in_sizes, int n_in,
                              void* d_out, int out_size, void* d_ws, size_t ws_size,
                              hipStream_t stream) {
  const float* enc = (const float*)d_in[0];
  const float* emb = (const float*)d_in[1];
  const unsigned char* smask = (const unsigned char*)d_in[2];
  const float* wq = (const float*)d_in[12]; const float* bq = (const float*)d_in[13];
  const float* wk = (const float*)d_in[14]; const float* bk = (const float*)d_in[15];
  const float* wv = (const float*)d_in[16]; const float* bv = (const float*)d_in[17];
  const float* wo = (const float*)d_in[18]; const float* bo = (const float*)d_in[19];
  const float* w1 = (const float*)d_in[20]; const float* b1 = (const float*)d_in[21];
  const float* w2 = (const float*)d_in[22]; const float* b2 = (const float*)d_in[23];
  const float* g1 = (const float*)d_in[26]; const float* be1 = (const float*)d_in[27];
  const float* g2 = (const float*)d_in[28]; const float* be2 = (const float*)d_in[29];

  char* ws = (char*)d_ws;
  const size_t MB = (size_t)1 << 20;
  bf16* wqkv_bf = (bf16*)(ws + 0 * MB);   // 3072x1024 packed (Q|K|V)
  bf16* wo_bf   = (bf16*)(ws + 6 * MB);
  bf16* w1_bf   = (bf16*)(ws + 8 * MB);
  bf16* w2_bf   = (bf16*)(ws + 16 * MB);
  bf16* enc_bf  = (bf16*)(ws + 24 * MB);
  bf16* z_bf    = enc_bf;                 // alias: enc_bf dead after QKV proj
  bf16* qin_bf  = (bf16*)(ws + 32 * MB);
  bf16* attn_bf = qin_bf;                 // alias: qin dead after QKV proj
  bf16* Q_bf    = (bf16*)(ws + 40 * MB);
  bf16* K_bf    = (bf16*)(ws + 48 * MB);
  bf16* Vt_bf   = (bf16*)(ws + 56 * MB);
  float* encdec = (float*)(ws + 64 * MB);
  bf16* h_bf    = (bf16*)(ws + 80 * MB);
  float* Po     = (float*)(ws + 112 * MB);  // 2 x 16MB O partials
  float* Pf     = (float*)(ws + 112 * MB);  // alias: Po dead after ln2

  // fused casts + LN1
  prep_kernel<<<20480, 256, 0, stream>>>(wq, wk, wv, wo, w1, w2, enc, emb, g1, be1,
                                         wqkv_bf, wo_bf, w1_bf, w2_bf, enc_bf, qin_bf);

  // fused Q|K|V projection: N=3072, 384 blocks
  {
    GP p{qin_bf, enc_bf, wqkv_bf, bq, bk, bv, Q_bf, K_bf, Vt_bf, 3072, DM, DM};
    gemm4<G_QKV><<<dim3(16, 24, 1), 512, 0, stream>>>(p);
  }

  // flash attention
  attn_kernel<<<512, 512, 0, stream>>>(Q_bf, K_bf, Vt_bf, smask, attn_bf);

  // O projection, split-K=2 -> partials
  {
    GP p{attn_bf, nullptr, wo_bf, nullptr, nullptr, nullptr, Po, nullptr, nullptr, DM, DM, DM / 2};
    gemm4<G_PART><<<dim3(16, 8, 2), 512, 0, stream>>>(p);
  }

  // LN2 + O-combine: encdec = Po0+Po1+bo+emb; z = LN(encdec)
  ln2_kernel<<<4096, 256, 0, stream>>>(Po, Po + (size_t)4096 * 1024, bo, emb, g2, be2,
                                       encdec, z_bf);

  // F1: 4096x4096, 512 blocks
  {
    GP p{z_bf, nullptr, w1_bf, b1, nullptr, nullptr, h_bf, nullptr, nullptr, DF, DM, DM};
    gemm4<G_F1><<<dim3(16, 32, 1), 512, 0, stream>>>(p);
  }

  // F2, split-K=2 -> partials
  {
    GP p{h_bf, nullptr, w2_bf, nullptr, nullptr, nullptr, Pf, nullptr, nullptr, DM, DF, DF / 2};
    gemm4<G_PART><<<dim3(16, 8, 2), 512, 0, stream>>>(p);
  }

  // final combine: d_out = Pf0+Pf1+b2+encdec
  fin_kernel<<<4096, 256, 0, stream>>>(Pf, Pf + (size_t)4096 * 1024, b2, encdec,
                                       (float*)d_out);
}